// Round 4
// baseline (819.546 us; speedup 1.0000x reference)
//
#include <hip/hip_runtime.h>

#define N_NODES 20000
#define N_EDGES 320000
#define SEQ 8

typedef __attribute__((ext_vector_type(8))) short bf16x8;
typedef __attribute__((ext_vector_type(4))) float floatx4;
typedef const unsigned int __attribute__((address_space(1)))* gas_u32;
typedef unsigned int __attribute__((address_space(3)))* las_u32;

__device__ __forceinline__ unsigned short f2bf(float f) {
  unsigned int u = __builtin_bit_cast(unsigned int, f);
  return (unsigned short)((u + 0x7fffu + ((u >> 16) & 1u)) >> 16);
}
__device__ __forceinline__ float bflo(unsigned int u) {
  return __builtin_bit_cast(float, u << 16);
}
__device__ __forceinline__ float bfhi(unsigned int u) {
  return __builtin_bit_cast(float, u & 0xffff0000u);
}
__device__ __forceinline__ float sigf(float x) { return 1.f / (1.f + __expf(-x)); }

// async global->LDS, 16B per lane; LDS dest = wave-uniform base + lane*16
__device__ __forceinline__ void gl_lds16(const void* g, void* l) {
  auto gp = (gas_u32)g;
  auto lp = (las_u32)(unsigned int)(unsigned long long)l;  // strip aperture
  __builtin_amdgcn_global_load_lds(gp, lp, 16, 0, 0);
}

// ---------------- setup kernels ----------------

// deg/counts init + weight transpose/convert. WiT[n][k]=Wi[k][n] (256x256).
// WcT combined 512x256 gate-interleaved: n'=4j+gate, orig=gate*128+j;
// k 0..255 spans [W1;W2] (Wc rows 0..255). bcp = b_cell permuted.
__global__ void k_prologue(const float* __restrict__ Wi,
                           const float* __restrict__ Wc,
                           const float* __restrict__ bc,
                           unsigned short* __restrict__ WiT,
                           unsigned short* __restrict__ WcT,
                           float* __restrict__ bcp,
                           float* __restrict__ deg, int* __restrict__ counts) {
  int idx = blockIdx.x * 256 + threadIdx.x;  // 0..131071
  if (idx < N_NODES) { deg[idx] = 1.0f; counts[idx] = 0; }
  if (idx < 65536) {
    int n = idx >> 8, k = idx & 255;
    WiT[n * 256 + k] = f2bf(Wi[k * 256 + n]);
  }
  if (idx < 512) bcp[idx] = bc[((idx & 3) << 7) | (idx >> 2)];
  int n2 = idx >> 8, k2 = idx & 255;  // n2 0..511, k2 0..255: full 512x256
  int orig = ((n2 & 3) << 7) | (n2 >> 2);
  WcT[n2 * 256 + k2] = f2bf(Wc[k2 * 512 + orig]);
}

__global__ void k_deg(const int* __restrict__ ei, const float* __restrict__ ea,
                      float* __restrict__ deg, int* __restrict__ counts) {
  int e = blockIdx.x * 256 + threadIdx.x;
  if (e >= N_EDGES) return;
  int d = ei[N_EDGES + e];
  atomicAdd(&deg[d], ea[e]);
  atomicAdd(&counts[d], 1);
}

// single-block scan: counts -> exclusive row_ptr/cursor; dinv = rsqrt(deg).
__global__ __launch_bounds__(1024) void k_scan(
    const int* __restrict__ counts, const float* __restrict__ deg,
    float* __restrict__ dinv, int* __restrict__ row_ptr,
    int* __restrict__ cursor) {
  __shared__ int smw[16];
  int t = threadIdx.x;
  int lane = t & 63, wv = t >> 6;
  int base = t * 20;
  int v[20];
  float dv[20];
  bool live = (t < 1000);
  if (live) {
    const int4* pc = (const int4*)(counts + base);
    const float4* pd = (const float4*)(deg + base);
#pragma unroll
    for (int i = 0; i < 5; ++i) {
      int4 q = pc[i];
      float4 f = pd[i];
      v[4 * i] = q.x; v[4 * i + 1] = q.y; v[4 * i + 2] = q.z; v[4 * i + 3] = q.w;
      dv[4 * i] = f.x; dv[4 * i + 1] = f.y; dv[4 * i + 2] = f.z; dv[4 * i + 3] = f.w;
    }
  } else {
#pragma unroll
    for (int i = 0; i < 20; ++i) { v[i] = 0; dv[i] = 1.f; }
  }
  int s = 0;
#pragma unroll
  for (int i = 0; i < 20; ++i) s += v[i];
  int inc = s;
#pragma unroll
  for (int o = 1; o < 64; o <<= 1) {
    int u = __shfl_up(inc, o);
    if (lane >= o) inc += u;
  }
  if (lane == 63) smw[wv] = inc;
  __syncthreads();
  if (t == 0) {
    int r = 0;
#pragma unroll
    for (int i = 0; i < 16; ++i) { int x = smw[i]; smw[i] = r; r += x; }
  }
  __syncthreads();
  int run = smw[wv] + inc - s;
  if (live) {
    int rp[20];
    float iv[20];
#pragma unroll
    for (int i = 0; i < 20; ++i) {
      rp[i] = run;
      run += v[i];
      iv[i] = rsqrtf(dv[i]);
    }
    int4* prp = (int4*)(row_ptr + base);
    int4* pcu = (int4*)(cursor + base);
    float4* pdv = (float4*)(dinv + base);
#pragma unroll
    for (int i = 0; i < 5; ++i) {
      int4 q; q.x = rp[4 * i]; q.y = rp[4 * i + 1]; q.z = rp[4 * i + 2]; q.w = rp[4 * i + 3];
      prp[i] = q;
      pcu[i] = q;
      float4 f; f.x = iv[4 * i]; f.y = iv[4 * i + 1]; f.z = iv[4 * i + 2]; f.w = iv[4 * i + 3];
      pdv[i] = f;
    }
  }
  if (t == 0) row_ptr[N_NODES] = N_EDGES;
}

// csr packed as int2 {src, bitcast(weight)}
__global__ void k_fill(const int* __restrict__ ei, const float* __restrict__ ea,
                       const float* __restrict__ dinv, int* __restrict__ cursor,
                       int2* __restrict__ csr) {
  int e = blockIdx.x * 256 + threadIdx.x;
  if (e >= N_EDGES) return;
  int s = ei[e], d = ei[N_EDGES + e];
  int k = atomicAdd(&cursor[d], 1);
  int2 p;
  p.x = s;
  p.y = __builtin_bit_cast(int, dinv[s] * ea[e] * dinv[d]);
  csr[k] = p;
}

// ---------------- init aggregation (fp32 h,c -> AhAc 256 bf16/row) ----------
__global__ __launch_bounds__(256) void k_agg_init(
    const float* __restrict__ h, const float* __restrict__ c,
    unsigned int* __restrict__ AhAc_u, const float* __restrict__ dinv,
    const int* __restrict__ row_ptr, const int2* __restrict__ csr) {
  int wid = (blockIdx.x * 256 + threadIdx.x) >> 6;
  int lane = threadIdx.x & 63;
  if (wid >= N_NODES) return;
  float di = dinv[wid], dd = di * di;
  const float4* xb = (lane < 32) ? (const float4*)h : (const float4*)c;
  int lcol = lane & 31;
  float4 a = xb[(size_t)wid * 32 + lcol];
  float s0 = a.x * dd, s1 = a.y * dd, s2 = a.z * dd, s3 = a.w * dd;
  int e0 = row_ptr[wid], end = row_ptr[wid + 1];
  for (int base = e0; base < end; base += 64) {
    int n = end - base;
    if (n > 64) n = 64;
    int sl = 0;
    float wl = 0.f;
    if (base + lane < end) {
      int2 p = csr[base + lane];
      sl = p.x;
      wl = __builtin_bit_cast(float, p.y);
    }
    int j = 0;
    for (; j + 4 <= n; j += 4) {
      int sa = __shfl(sl, j), sb = __shfl(sl, j + 1);
      int sc = __shfl(sl, j + 2), sd = __shfl(sl, j + 3);
      float wa = __shfl(wl, j), wb = __shfl(wl, j + 1);
      float wc = __shfl(wl, j + 2), wd = __shfl(wl, j + 3);
      float4 va = xb[(size_t)sa * 32 + lcol];
      float4 vb = xb[(size_t)sb * 32 + lcol];
      float4 vc = xb[(size_t)sc * 32 + lcol];
      float4 vd = xb[(size_t)sd * 32 + lcol];
      s0 += va.x * wa; s1 += va.y * wa; s2 += va.z * wa; s3 += va.w * wa;
      s0 += vb.x * wb; s1 += vb.y * wb; s2 += vb.z * wb; s3 += vb.w * wb;
      s0 += vc.x * wc; s1 += vc.y * wc; s2 += vc.z * wc; s3 += vc.w * wc;
      s0 += vd.x * wd; s1 += vd.y * wd; s2 += vd.z * wd; s3 += vd.w * wd;
    }
    for (; j < n; ++j) {
      int sa = __shfl(sl, j);
      float wa = __shfl(wl, j);
      float4 va = xb[(size_t)sa * 32 + lcol];
      s0 += va.x * wa; s1 += va.y * wa; s2 += va.z * wa; s3 += va.w * wa;
    }
  }
  uint2 o;
  o.x = (unsigned int)f2bf(s0) | ((unsigned int)f2bf(s1) << 16);
  o.y = (unsigned int)f2bf(s2) | ((unsigned int)f2bf(s3) << 16);
  ((uint2*)AhAc_u)[(size_t)wid * 64 + lane] = o;
}

// ---------------- init GEMM (elu epilogue -> hbf0, c_cur) --------------------
__global__ __launch_bounds__(256) void k_gemm0(
    const unsigned short* __restrict__ A, const unsigned short* __restrict__ BT,
    const float* __restrict__ bias, float* __restrict__ c_cur,
    unsigned short* __restrict__ hbf) {
  __shared__ __align__(16) struct { unsigned short a[128 * 64]; unsigned short b[128 * 64]; } sm;
  const int M = N_NODES;
  int tid = threadIdx.x;
  int bm0 = blockIdx.x * 128, bn0 = blockIdx.y * 128;
  int wave = tid >> 6, lane = tid & 63;
  int wrow = (wave >> 1) * 64, wcol = (wave & 1) * 64;
  int lr = lane & 15, lq = lane >> 4;
  int key = lr & 7;
  int lr8 = lane >> 3, cq = lane & 7;
  int gq8 = (cq ^ lr8) * 8;

  floatx4 acc[4][4];
#pragma unroll
  for (int i = 0; i < 4; i++)
#pragma unroll
    for (int j = 0; j < 4; j++) acc[i][j] = (floatx4){0.f, 0.f, 0.f, 0.f};

  for (int k0 = 0; k0 < 256; k0 += 64) {
    __syncthreads();
#pragma unroll
    for (int p = 0; p < 4; ++p) {
      int row = p * 32 + wave * 8;
      int ra = bm0 + row + lr8;
      if (ra > M - 1) ra = M - 1;
      gl_lds16(A + (size_t)ra * 256 + k0 + gq8, sm.a + row * 64);
      gl_lds16(BT + (size_t)(bn0 + row + lr8) * 256 + k0 + gq8, sm.b + row * 64);
    }
    __syncthreads();
#pragma unroll
    for (int ks = 0; ks < 2; ++ks) {
      int q = ks * 4 + lq;
      int slot = (q ^ key) << 3;
      bf16x8 af[4], bfr[4];
#pragma unroll
      for (int mi = 0; mi < 4; mi++)
        af[mi] = *(const bf16x8*)(sm.a + (wrow + mi * 16 + lr) * 64 + slot);
#pragma unroll
      for (int ni = 0; ni < 4; ni++)
        bfr[ni] = *(const bf16x8*)(sm.b + (wcol + ni * 16 + lr) * 64 + slot);
#pragma unroll
      for (int mi = 0; mi < 4; mi++)
#pragma unroll
        for (int ni = 0; ni < 4; ni++)
          acc[mi][ni] = __builtin_amdgcn_mfma_f32_16x16x32_bf16(
              af[mi], bfr[ni], acc[mi][ni], 0, 0, 0);
    }
  }

#pragma unroll
  for (int mi = 0; mi < 4; mi++) {
#pragma unroll
    for (int r = 0; r < 4; r++) {
      int grow = bm0 + wrow + mi * 16 + lq * 4 + r;
      if (grow >= M) continue;
#pragma unroll
      for (int ni = 0; ni < 4; ni++) {
        int gcol = bn0 + wcol + ni * 16 + lr;
        float v = acc[mi][ni][r] + bias[gcol];
        v = (v > 0.f) ? v : expm1f(v);
        if (gcol < 128) hbf[(size_t)grow * 128 + gcol] = f2bf(v);
        else c_cur[(size_t)grow * 128 + gcol - 128] = v;
      }
    }
  }
}

// ---------------- fused per-step kernel --------------------------------------
// One block per 128-row slab (157 blocks x 512 threads = 8 waves).
// No inter-block dependencies: reads hr (prev step's h, bf16), writes hw
// (double-buffered), c_cur/out rows owned exclusively by this block.
// Phase A: issue async Ah staging (LDS chunks 0,1) + gather Aht straight into
//          LDS chunks 2,3 in the XOR-swizzled layout (never touches global).
// Phase B: 4 x (128x128 gate-tile): pair-staged WcT chunks, MFMA K=256.
// Phase C: fused LSTM epilogue per tile via LDS transpose.
__global__ __launch_bounds__(512) void k_step(
    const int2* __restrict__ csr, const int* __restrict__ row_ptr,
    const float* __restrict__ dinv, const unsigned short* __restrict__ AhAc,
    const unsigned short* __restrict__ WcT, const float* __restrict__ bcp,
    float* __restrict__ c_cur, const unsigned int* __restrict__ hr,
    unsigned short* __restrict__ hw, float* __restrict__ out0) {
  __shared__ __align__(16) unsigned short smA[4][128 * 64];  // 64 KB, A chunks
  __shared__ __align__(16) unsigned short smB[2][128 * 64];  // 32 KB, B pair
  __shared__ __align__(16) float ep[64 * 132];               // 33.8 KB
  const int M = N_NODES;
  int tid = threadIdx.x;
  int bm0 = blockIdx.x * 128;
  int wave = tid >> 6, lane = tid & 63;
  int wr = wave >> 2, wc = wave & 3;
  int wrow = wr * 64, wcol = wc * 32;
  int lr = lane & 15, lq = lane >> 4;
  int key = lr & 7;
  int lr8 = lane >> 3, cq = lane & 7;
  int gq8 = (cq ^ lr8) * 8;  // pre-swizzled global chunk offset (shorts)

  // ---- Phase A1: issue async Ah staging (chunks 0,1) -- hides under gather
#pragma unroll
  for (int p = 0; p < 2; ++p) {
#pragma unroll
    for (int kc = 0; kc < 2; ++kc) {
      int row = p * 64 + wave * 8;  // wave-uniform base row
      int ra = bm0 + row + lr8;
      if (ra > M - 1) ra = M - 1;  // clamp: junk rows never stored
      gl_lds16(AhAc + (size_t)ra * 256 + kc * 64 + gq8, smA[kc] + row * 64);
    }
  }

  // ---- Phase A2: gather 16 nodes per wave, write swizzled into smA[2],[3]
  {
    int kcw = 2 + (lane >> 5);        // dest chunk
    int cc2 = (lane * 2) & 63;        // position within chunk (shorts)
    int grp = cc2 >> 3, el = cc2 & 7;
    for (int rl = wave * 16; rl < wave * 16 + 16; ++rl) {
      int wid = bm0 + rl;
      if (wid >= N_NODES) continue;
      float di = dinv[wid], dd = di * di;
      unsigned int a = hr[(size_t)wid * 64 + lane];
      float s0 = bflo(a) * dd, s1 = bfhi(a) * dd;
      int e0 = row_ptr[wid], end = row_ptr[wid + 1];
      for (int base = e0; base < end; base += 64) {
        int n = end - base;
        if (n > 64) n = 64;
        int sl = 0;
        float wl = 0.f;
        if (base + lane < end) {
          int2 p = csr[base + lane];
          sl = p.x;
          wl = __builtin_bit_cast(float, p.y);
        }
        int j = 0;
        for (; j + 4 <= n; j += 4) {
          int sa = __shfl(sl, j), sb = __shfl(sl, j + 1);
          int sc = __shfl(sl, j + 2), sd = __shfl(sl, j + 3);
          float wa = __shfl(wl, j), wb = __shfl(wl, j + 1);
          float wcv = __shfl(wl, j + 2), wd = __shfl(wl, j + 3);
          unsigned int va = hr[(size_t)sa * 64 + lane];
          unsigned int vb = hr[(size_t)sb * 64 + lane];
          unsigned int vc = hr[(size_t)sc * 64 + lane];
          unsigned int vd = hr[(size_t)sd * 64 + lane];
          s0 += bflo(va) * wa; s1 += bfhi(va) * wa;
          s0 += bflo(vb) * wb; s1 += bfhi(vb) * wb;
          s0 += bflo(vc) * wcv; s1 += bfhi(vc) * wcv;
          s0 += bflo(vd) * wd; s1 += bfhi(vd) * wd;
        }
        for (; j < n; ++j) {
          int sa = __shfl(sl, j);
          float wa = __shfl(wl, j);
          unsigned int va = hr[(size_t)sa * 64 + lane];
          s0 += bflo(va) * wa; s1 += bfhi(va) * wa;
        }
      }
      // swizzled LDS write: global group grp lives at LDS group grp^(row&7)
      int lidx = rl * 64 + ((grp ^ (rl & 7)) << 3) + el;  // even -> 4B aligned
      unsigned int packed =
          (unsigned int)f2bf(s0) | ((unsigned int)f2bf(s1) << 16);
      *(unsigned int*)&smA[kcw][lidx] = packed;
    }
  }

  // ---- Phase B/C: 4 gate-tiles of 128x128, K=256
  for (int bn = 0; bn < 4; ++bn) {
    int bn0 = bn * 128;
    floatx4 acc[4][2];
#pragma unroll
    for (int i = 0; i < 4; i++)
#pragma unroll
      for (int j = 0; j < 2; j++) acc[i][j] = (floatx4){0.f, 0.f, 0.f, 0.f};

#pragma unroll
    for (int kp = 0; kp < 2; ++kp) {
      __syncthreads();  // smB free (prev pair consumed); 1st iter: A ready
#pragma unroll
      for (int cc = 0; cc < 2; ++cc) {
        int kc = kp * 2 + cc;
#pragma unroll
        for (int p = 0; p < 2; ++p) {
          int row = p * 64 + wave * 8;
          gl_lds16(WcT + (size_t)(bn0 + row + lr8) * 256 + kc * 64 + gq8,
                   smB[cc] + row * 64);
        }
      }
      __syncthreads();  // staged (vmcnt drained)
#pragma unroll
      for (int cc = 0; cc < 2; ++cc) {
        int kc = kp * 2 + cc;
#pragma unroll
        for (int ks = 0; ks < 2; ++ks) {
          int q = ks * 4 + lq;
          int slot = (q ^ key) << 3;
          bf16x8 af[4], bfr[2];
#pragma unroll
          for (int mi = 0; mi < 4; mi++)
            af[mi] = *(const bf16x8*)(smA[kc] + (wrow + mi * 16 + lr) * 64 + slot);
#pragma unroll
          for (int ni = 0; ni < 2; ni++)
            bfr[ni] = *(const bf16x8*)(smB[cc] + (wcol + ni * 16 + lr) * 64 + slot);
#pragma unroll
          for (int mi = 0; mi < 4; mi++)
#pragma unroll
            for (int ni = 0; ni < 2; ni++)
              acc[mi][ni] = __builtin_amdgcn_mfma_f32_16x16x32_bf16(
                  af[mi], bfr[ni], acc[mi][ni], 0, 0, 0);
        }
      }
    }

    // epilogue: two 64-row chunks through LDS transpose; fused LSTM gates
#pragma unroll
    for (int hch = 0; hch < 2; ++hch) {
      __syncthreads();  // ep free (prev consume done / prev bn done)
      if (wr == hch) {
#pragma unroll
        for (int mi = 0; mi < 4; mi++)
#pragma unroll
          for (int r = 0; r < 4; r++) {
            int row_l = mi * 16 + lq * 4 + r;
#pragma unroll
            for (int ni = 0; ni < 2; ni++)
              ep[row_l * 132 + wcol + ni * 16 + lr] = acc[mi][ni][r];
          }
      }
      __syncthreads();
#pragma unroll
      for (int it = 0; it < 4; ++it) {
        int p = tid + it * 512;
        int row_l = p >> 5, j = p & 31;
        int grow = bm0 + hch * 64 + row_l;
        if (grow < M) {
          int jg = (bn0 >> 2) + j;  // h-col = bn*32 + j
          const float* eb = ep + row_l * 132 + 4 * j;
          float4 kb = *(const float4*)&bcp[bn0 + 4 * j];
          float gi = eb[0] + kb.x;
          float gf = eb[1] + kb.y;
          float go = eb[2] + kb.z;
          float gg = eb[3] + kb.w;
          size_t o = (size_t)grow * 128 + jg;
          float cp = c_cur[o];
          float cn = sigf(gf) * cp + sigf(gi) * tanhf(gg);
          float hn = sigf(go) * tanhf(cn);
          c_cur[o] = cn;
          hw[o] = f2bf(hn);
          out0[o] = hn;
        }
      }
    }
  }
}

// ---------------- host launcher ----------------
extern "C" void kernel_launch(void* const* d_in, const int* in_sizes, int n_in,
                              void* d_out, int out_size, void* d_ws, size_t ws_size,
                              hipStream_t stream) {
  const float* h  = (const float*)d_in[0];
  const float* c  = (const float*)d_in[1];
  const int*   ei = (const int*)d_in[2];
  const float* ea = (const float*)d_in[3];
  const float* Wi = (const float*)d_in[4];
  const float* bi = (const float*)d_in[5];
  const float* Wc = (const float*)d_in[6];
  const float* bc = (const float*)d_in[7];
  float* out = (float*)d_out;

  char* w = (char*)d_ws;
  size_t off = 0;
  auto alloc = [&](size_t bytes) {
    void* p = w + off;
    off += (bytes + 511) & ~(size_t)511;
    return p;
  };
  float* deg           = (float*)alloc(N_NODES * 4);
  float* dinv          = (float*)alloc(N_NODES * 4);
  int* counts          = (int*)alloc(N_NODES * 4);
  int* cursor          = (int*)alloc(N_NODES * 4);
  int* row_ptr         = (int*)alloc((N_NODES + 1) * 4);
  int2* csr            = (int2*)alloc((size_t)N_EDGES * 8);
  unsigned short* WiT  = (unsigned short*)alloc(256 * 256 * 2);
  unsigned short* WcT  = (unsigned short*)alloc(512 * 256 * 2);
  float* bcp           = (float*)alloc(512 * 4);
  unsigned short* AhAc = (unsigned short*)alloc((size_t)N_NODES * 256 * 2);
  unsigned short* hbfA = (unsigned short*)alloc((size_t)N_NODES * 128 * 2);
  unsigned short* hbfB = (unsigned short*)alloc((size_t)N_NODES * 128 * 2);
  float* c_cur         = (float*)alloc((size_t)N_NODES * 128 * 4);

  const int NB_E = (N_EDGES + 255) / 256;  // 1250
  const int NB_AGG = N_NODES * 64 / 256;   // 5000
  const int MB = (N_NODES + 127) / 128;    // 157

  k_prologue<<<512, 256, 0, stream>>>(Wi, Wc, bc, WiT, WcT, bcp, deg, counts);
  k_deg<<<NB_E, 256, 0, stream>>>(ei, ea, deg, counts);
  k_scan<<<1, 1024, 0, stream>>>(counts, deg, dinv, row_ptr, cursor);
  k_fill<<<NB_E, 256, 0, stream>>>(ei, ea, dinv, cursor, csr);

  k_agg_init<<<NB_AGG, 256, 0, stream>>>(h, c, (unsigned int*)AhAc, dinv,
                                         row_ptr, csr);
  // states = elu([Ah|Ac]@Wi + bi) -> hbfA, c_cur
  k_gemm0<<<dim3(MB, 2), 256, 0, stream>>>(AhAc, WiT, bi, c_cur, hbfA);

  for (int t = 0; t < SEQ; ++t) {
    const unsigned short* hr = (t & 1) ? hbfB : hbfA;
    unsigned short* hw = (t & 1) ? hbfA : hbfB;
    k_step<<<MB, 512, 0, stream>>>(csr, row_ptr, dinv, AhAc, WcT, bcp, c_cur,
                                   (const unsigned int*)hr, hw,
                                   out + (size_t)t * N_NODES * 128);
  }
}

// Round 6
// 500.567 us; speedup vs baseline: 1.6372x; 1.6372x over previous
//
#include <hip/hip_runtime.h>

#define N_NODES 20000
#define N_EDGES 320000
#define SEQ 8

typedef __attribute__((ext_vector_type(8))) short bf16x8;
typedef __attribute__((ext_vector_type(4))) float floatx4;
typedef const unsigned int __attribute__((address_space(1)))* gas_u32;
typedef unsigned int __attribute__((address_space(3)))* las_u32;

__device__ __forceinline__ unsigned short f2bf(float f) {
  unsigned int u = __builtin_bit_cast(unsigned int, f);
  return (unsigned short)((u + 0x7fffu + ((u >> 16) & 1u)) >> 16);
}
__device__ __forceinline__ float bflo(unsigned int u) {
  return __builtin_bit_cast(float, u << 16);
}
__device__ __forceinline__ float bfhi(unsigned int u) {
  return __builtin_bit_cast(float, u & 0xffff0000u);
}
__device__ __forceinline__ float sigf(float x) { return 1.f / (1.f + __expf(-x)); }

// async global->LDS, 16B per lane; LDS dest = wave-uniform base + lane*16
__device__ __forceinline__ void gl_lds16(const void* g, void* l) {
  auto gp = (gas_u32)g;
  auto lp = (las_u32)(unsigned int)(unsigned long long)l;  // strip aperture
  __builtin_amdgcn_global_load_lds(gp, lp, 16, 0, 0);
}

// ---------------- setup kernels ----------------

// deg/counts init + weight transpose/convert. WiT[n][k]=Wi[k][n] (256x256).
// WcT combined 512x256 gate-interleaved: n'=4j+gate, orig=gate*128+j;
// k 0..255 spans [W1;W2] (Wc rows 0..255). bcp = b_cell permuted.
__global__ void k_prologue(const float* __restrict__ Wi,
                           const float* __restrict__ Wc,
                           const float* __restrict__ bc,
                           unsigned short* __restrict__ WiT,
                           unsigned short* __restrict__ WcT,
                           float* __restrict__ bcp,
                           float* __restrict__ deg, int* __restrict__ counts) {
  int idx = blockIdx.x * 256 + threadIdx.x;  // 0..131071
  if (idx < N_NODES) { deg[idx] = 1.0f; counts[idx] = 0; }
  if (idx < 65536) {
    int n = idx >> 8, k = idx & 255;
    WiT[n * 256 + k] = f2bf(Wi[k * 256 + n]);
  }
  if (idx < 512) bcp[idx] = bc[((idx & 3) << 7) | (idx >> 2)];
  int n2 = idx >> 8, k2 = idx & 255;  // n2 0..511, k2 0..255: full 512x256
  int orig = ((n2 & 3) << 7) | (n2 >> 2);
  WcT[n2 * 256 + k2] = f2bf(Wc[k2 * 512 + orig]);
}

__global__ void k_deg(const int* __restrict__ ei, const float* __restrict__ ea,
                      float* __restrict__ deg, int* __restrict__ counts) {
  int e = blockIdx.x * 256 + threadIdx.x;
  if (e >= N_EDGES) return;
  int d = ei[N_EDGES + e];
  atomicAdd(&deg[d], ea[e]);
  atomicAdd(&counts[d], 1);
}

// single-block scan: counts -> exclusive row_ptr/cursor; dinv = rsqrt(deg).
__global__ __launch_bounds__(1024) void k_scan(
    const int* __restrict__ counts, const float* __restrict__ deg,
    float* __restrict__ dinv, int* __restrict__ row_ptr,
    int* __restrict__ cursor) {
  __shared__ int smw[16];
  int t = threadIdx.x;
  int lane = t & 63, wv = t >> 6;
  int base = t * 20;
  int v[20];
  float dv[20];
  bool live = (t < 1000);
  if (live) {
    const int4* pc = (const int4*)(counts + base);
    const float4* pd = (const float4*)(deg + base);
#pragma unroll
    for (int i = 0; i < 5; ++i) {
      int4 q = pc[i];
      float4 f = pd[i];
      v[4 * i] = q.x; v[4 * i + 1] = q.y; v[4 * i + 2] = q.z; v[4 * i + 3] = q.w;
      dv[4 * i] = f.x; dv[4 * i + 1] = f.y; dv[4 * i + 2] = f.z; dv[4 * i + 3] = f.w;
    }
  } else {
#pragma unroll
    for (int i = 0; i < 20; ++i) { v[i] = 0; dv[i] = 1.f; }
  }
  int s = 0;
#pragma unroll
  for (int i = 0; i < 20; ++i) s += v[i];
  int inc = s;
#pragma unroll
  for (int o = 1; o < 64; o <<= 1) {
    int u = __shfl_up(inc, o);
    if (lane >= o) inc += u;
  }
  if (lane == 63) smw[wv] = inc;
  __syncthreads();
  if (t == 0) {
    int r = 0;
#pragma unroll
    for (int i = 0; i < 16; ++i) { int x = smw[i]; smw[i] = r; r += x; }
  }
  __syncthreads();
  int run = smw[wv] + inc - s;
  if (live) {
    int rp[20];
    float iv[20];
#pragma unroll
    for (int i = 0; i < 20; ++i) {
      rp[i] = run;
      run += v[i];
      iv[i] = rsqrtf(dv[i]);
    }
    int4* prp = (int4*)(row_ptr + base);
    int4* pcu = (int4*)(cursor + base);
    float4* pdv = (float4*)(dinv + base);
#pragma unroll
    for (int i = 0; i < 5; ++i) {
      int4 q; q.x = rp[4 * i]; q.y = rp[4 * i + 1]; q.z = rp[4 * i + 2]; q.w = rp[4 * i + 3];
      prp[i] = q;
      pcu[i] = q;
      float4 f; f.x = iv[4 * i]; f.y = iv[4 * i + 1]; f.z = iv[4 * i + 2]; f.w = iv[4 * i + 3];
      pdv[i] = f;
    }
  }
  if (t == 0) row_ptr[N_NODES] = N_EDGES;
}

// csr packed as int2 {src, bitcast(weight)}
__global__ void k_fill(const int* __restrict__ ei, const float* __restrict__ ea,
                       const float* __restrict__ dinv, int* __restrict__ cursor,
                       int2* __restrict__ csr) {
  int e = blockIdx.x * 256 + threadIdx.x;
  if (e >= N_EDGES) return;
  int s = ei[e], d = ei[N_EDGES + e];
  int k = atomicAdd(&cursor[d], 1);
  int2 p;
  p.x = s;
  p.y = __builtin_bit_cast(int, dinv[s] * ea[e] * dinv[d]);
  csr[k] = p;
}

// ---------------- aggregation --------------------------------------------

// init: one wave per node; gather fp32 h,c -> AhAc rows (256 bf16)
__global__ __launch_bounds__(256) void k_agg_init(
    const float* __restrict__ h, const float* __restrict__ c,
    unsigned int* __restrict__ AhAc_u, const float* __restrict__ dinv,
    const int* __restrict__ row_ptr, const int2* __restrict__ csr) {
  int wid = (blockIdx.x * 256 + threadIdx.x) >> 6;
  int lane = threadIdx.x & 63;
  if (wid >= N_NODES) return;
  float di = dinv[wid], dd = di * di;
  const float4* xb = (lane < 32) ? (const float4*)h : (const float4*)c;
  int lcol = lane & 31;
  float4 a = xb[(size_t)wid * 32 + lcol];
  float s0 = a.x * dd, s1 = a.y * dd, s2 = a.z * dd, s3 = a.w * dd;
  int e0 = row_ptr[wid], end = row_ptr[wid + 1];
  for (int base = e0; base < end; base += 64) {
    int n = end - base;
    if (n > 64) n = 64;
    int sl = 0;
    float wl = 0.f;
    if (base + lane < end) {
      int2 p = csr[base + lane];
      sl = p.x;
      wl = __builtin_bit_cast(float, p.y);
    }
    int j = 0;
    for (; j + 4 <= n; j += 4) {
      int sa = __shfl(sl, j), sb = __shfl(sl, j + 1);
      int sc = __shfl(sl, j + 2), sd = __shfl(sl, j + 3);
      float wa = __shfl(wl, j), wb = __shfl(wl, j + 1);
      float wc = __shfl(wl, j + 2), wd = __shfl(wl, j + 3);
      float4 va = xb[(size_t)sa * 32 + lcol];
      float4 vb = xb[(size_t)sb * 32 + lcol];
      float4 vc = xb[(size_t)sc * 32 + lcol];
      float4 vd = xb[(size_t)sd * 32 + lcol];
      s0 += va.x * wa; s1 += va.y * wa; s2 += va.z * wa; s3 += va.w * wa;
      s0 += vb.x * wb; s1 += vb.y * wb; s2 += vb.z * wb; s3 += vb.w * wb;
      s0 += vc.x * wc; s1 += vc.y * wc; s2 += vc.z * wc; s3 += vc.w * wc;
      s0 += vd.x * wd; s1 += vd.y * wd; s2 += vd.z * wd; s3 += vd.w * wd;
    }
    for (; j < n; ++j) {
      int sa = __shfl(sl, j);
      float wa = __shfl(wl, j);
      float4 va = xb[(size_t)sa * 32 + lcol];
      s0 += va.x * wa; s1 += va.y * wa; s2 += va.z * wa; s3 += va.w * wa;
    }
  }
  uint2 o;
  o.x = (unsigned int)f2bf(s0) | ((unsigned int)f2bf(s1) << 16);
  o.y = (unsigned int)f2bf(s2) | ((unsigned int)f2bf(s3) << 16);
  ((uint2*)AhAc_u)[(size_t)wid * 64 + lane] = o;
}

// step: TWO nodes per wave (lanes 0-31 node 2w, lanes 32-63 node 2w+1).
// Each lane handles 2 u32 (4 bf16 cols) via uint2. Halves the gather/CSR
// instruction count and doubles per-wave MLP. Per-column accumulation chain
// is identical to the 1-node version (self term, then edges in csr order;
// masked lanes add exact v*0.0) -> bit-identical output.
__global__ __launch_bounds__(256) void k_agg_step(
    const unsigned int* __restrict__ hbf_u, unsigned int* __restrict__ AhAc_u,
    const float* __restrict__ dinv, const int* __restrict__ row_ptr,
    const int2* __restrict__ csr) {
  int wp = (blockIdx.x * 256 + threadIdx.x) >> 6;  // wave-pair id
  int lane = threadIdx.x & 63;
  int half = lane >> 5;            // 0: node 2wp, 1: node 2wp+1
  int hl = lane & 31;
  int node = wp * 2 + half;
  if (node >= N_NODES) return;     // N_NODES even: wave-uniform exit
  float di = dinv[node], dd = di * di;
  const uint2* hb2 = (const uint2*)hbf_u;  // row = 32 x uint2 (256B)
  uint2 a2 = hb2[(size_t)node * 32 + hl];
  float s0 = bflo(a2.x) * dd, s1 = bfhi(a2.x) * dd;
  float s2 = bflo(a2.y) * dd, s3 = bfhi(a2.y) * dd;
  int e0 = row_ptr[node];
  int deg = row_ptr[node + 1] - e0;
  int mdeg = max(__shfl(deg, 0), __shfl(deg, 32));  // wave-uniform bound
  int off = half << 5;  // shfl base: broadcast from own half

  for (int base = 0; base < mdeg; base += 32) {
    int sl = 0;
    float wl = 0.f;
    if (base + hl < deg) {  // per-half coalesced 256B chunk
      int2 p = csr[e0 + base + hl];
      sl = p.x;
      wl = __builtin_bit_cast(float, p.y);
    }
    int n = mdeg - base;
    if (n > 32) n = 32;
    int j = 0;
    for (; j + 4 <= n; j += 4) {
      int sa = __shfl(sl, off + j), sb = __shfl(sl, off + j + 1);
      int sc = __shfl(sl, off + j + 2), sd = __shfl(sl, off + j + 3);
      float wa = __shfl(wl, off + j), wb = __shfl(wl, off + j + 1);
      float wc = __shfl(wl, off + j + 2), wd = __shfl(wl, off + j + 3);
      uint2 va = hb2[(size_t)sa * 32 + hl];
      uint2 vb = hb2[(size_t)sb * 32 + hl];
      uint2 vc = hb2[(size_t)sc * 32 + hl];
      uint2 vd = hb2[(size_t)sd * 32 + hl];
      s0 += bflo(va.x) * wa; s1 += bfhi(va.x) * wa;
      s2 += bflo(va.y) * wa; s3 += bfhi(va.y) * wa;
      s0 += bflo(vb.x) * wb; s1 += bfhi(vb.x) * wb;
      s2 += bflo(vb.y) * wb; s3 += bfhi(vb.y) * wb;
      s0 += bflo(vc.x) * wc; s1 += bfhi(vc.x) * wc;
      s2 += bflo(vc.y) * wc; s3 += bfhi(vc.y) * wc;
      s0 += bflo(vd.x) * wd; s1 += bfhi(vd.x) * wd;
      s2 += bflo(vd.y) * wd; s3 += bfhi(vd.y) * wd;
    }
    for (; j < n; ++j) {
      int sa = __shfl(sl, off + j);
      float wa = __shfl(wl, off + j);
      uint2 va = hb2[(size_t)sa * 32 + hl];
      s0 += bflo(va.x) * wa; s1 += bfhi(va.x) * wa;
      s2 += bflo(va.y) * wa; s3 += bfhi(va.y) * wa;
    }
  }
  uint2 o;
  o.x = (unsigned int)f2bf(s0) | ((unsigned int)f2bf(s1) << 16);
  o.y = (unsigned int)f2bf(s2) | ((unsigned int)f2bf(s3) << 16);
  // Aht = AhAc cols 128..255: u32 index node*128 + 64 + 2*hl -> uint2 idx
  ((uint2*)AhAc_u)[(size_t)node * 64 + 32 + hl] = o;
}

// ---------------- bf16 MFMA GEMM with global_load_lds + XOR-swizzled LDS -----
// C[128x128] = A[128xKK](row-stride LDA) @ BT[128 of KK]^T + epilogue.
// EPI 0 (init, KK=256): v += bias[gcol]; elu; col<128 -> hbf else c_cur.
// EPI 2 (step, KK=256): gates fused; gi..gg = acc + bcp[gcol] (bias).
template <int EPI, int KK, int LDA>
__global__ __launch_bounds__(256) void k_gemm(
    const unsigned short* __restrict__ A, const unsigned short* __restrict__ BT,
    const float* __restrict__ bias,
    float* __restrict__ c_cur, unsigned short* __restrict__ hbf,
    float* __restrict__ out0) {
  __shared__ __align__(16) union {
    struct { unsigned short a[128 * 64]; unsigned short b[128 * 64]; } ab;
    float ep[64 * 132];
  } sm;
  const int M = N_NODES;
  int tid = threadIdx.x;
  int bm0 = blockIdx.x * 128, bn0 = blockIdx.y * 128;
  int wave = tid >> 6, lane = tid & 63;
  int wrow = (wave >> 1) * 64, wcol = (wave & 1) * 64;
  int lr = lane & 15, lq = lane >> 4;
  int key = lr & 7;

  // staging lane roles: 8 lanes/row, 8 rows/wave/call
  int lr8 = lane >> 3, cq = lane & 7;
  int gq8 = (cq ^ lr8) * 8;  // swizzled global chunk offset (shorts)

  floatx4 acc[4][4];
#pragma unroll
  for (int i = 0; i < 4; i++)
#pragma unroll
    for (int j = 0; j < 4; j++) acc[i][j] = (floatx4){0.f, 0.f, 0.f, 0.f};

  for (int k0 = 0; k0 < KK; k0 += 64) {
    __syncthreads();
#pragma unroll
    for (int p = 0; p < 4; ++p) {
      int row = p * 32 + wave * 8;        // wave-uniform base row
      int ra = bm0 + row + lr8;
      if (ra > M - 1) ra = M - 1;         // clamp: junk rows never stored
      gl_lds16(A + (size_t)ra * LDA + k0 + gq8, sm.ab.a + row * 64);
      gl_lds16(BT + (size_t)(bn0 + row + lr8) * KK + k0 + gq8,
               sm.ab.b + row * 64);
    }
    __syncthreads();
#pragma unroll
    for (int ks = 0; ks < 2; ++ks) {
      int q = ks * 4 + lq;
      int slot = (q ^ key) << 3;
      bf16x8 af[4], bfr[4];
#pragma unroll
      for (int mi = 0; mi < 4; mi++)
        af[mi] = *(const bf16x8*)(sm.ab.a + (wrow + mi * 16 + lr) * 64 + slot);
#pragma unroll
      for (int ni = 0; ni < 4; ni++)
        bfr[ni] = *(const bf16x8*)(sm.ab.b + (wcol + ni * 16 + lr) * 64 + slot);
#pragma unroll
      for (int mi = 0; mi < 4; mi++)
#pragma unroll
        for (int ni = 0; ni < 4; ni++)
          acc[mi][ni] = __builtin_amdgcn_mfma_f32_16x16x32_bf16(
              af[mi], bfr[ni], acc[mi][ni], 0, 0, 0);
    }
  }
  __syncthreads();  // sm.ab dead before epilogue reuse

  if (EPI == 0) {
#pragma unroll
    for (int mi = 0; mi < 4; mi++) {
#pragma unroll
      for (int r = 0; r < 4; r++) {
        int grow = bm0 + wrow + mi * 16 + lq * 4 + r;
        if (grow >= M) continue;
#pragma unroll
        for (int ni = 0; ni < 4; ni++) {
          int gcol = bn0 + wcol + ni * 16 + lr;
          float v = acc[mi][ni][r] + bias[gcol];
          v = (v > 0.f) ? v : expm1f(v);
          if (gcol < 128) hbf[(size_t)grow * 128 + gcol] = f2bf(v);
          else c_cur[(size_t)grow * 128 + gcol - 128] = v;
        }
      }
    }
  } else {
    // two 64-row chunks through LDS transpose; fused LSTM gates
#pragma unroll
    for (int hch = 0; hch < 2; ++hch) {
      if ((wrow >> 6) == hch) {
#pragma unroll
        for (int mi = 0; mi < 4; mi++)
#pragma unroll
          for (int r = 0; r < 4; r++) {
            int row_l = mi * 16 + lq * 4 + r;
#pragma unroll
            for (int ni = 0; ni < 4; ni++)
              sm.ep[row_l * 132 + wcol + ni * 16 + lr] = acc[mi][ni][r];
          }
      }
      __syncthreads();
#pragma unroll
      for (int it = 0; it < 8; ++it) {
        int p = tid + it * 256;
        int row_l = p >> 5, j = p & 31;
        int grow = bm0 + hch * 64 + row_l;
        if (grow < M) {
          int jg = (bn0 >> 2) + j;
          const float* eb = sm.ep + row_l * 132 + 4 * j;
          float4 kb = *(const float4*)&bias[bn0 + 4 * j];  // bcp (gate-interleaved)
          float gi = eb[0] + kb.x;
          float gf = eb[1] + kb.y;
          float go = eb[2] + kb.z;
          float gg = eb[3] + kb.w;
          size_t o = (size_t)grow * 128 + jg;
          float cp = c_cur[o];
          float cn = sigf(gf) * cp + sigf(gi) * tanhf(gg);
          float hn = sigf(go) * tanhf(cn);
          c_cur[o] = cn;
          hbf[o] = f2bf(hn);
          out0[o] = hn;
        }
      }
      __syncthreads();
    }
  }
}

// ---------------- host launcher ----------------
extern "C" void kernel_launch(void* const* d_in, const int* in_sizes, int n_in,
                              void* d_out, int out_size, void* d_ws, size_t ws_size,
                              hipStream_t stream) {
  const float* h  = (const float*)d_in[0];
  const float* c  = (const float*)d_in[1];
  const int*   ei = (const int*)d_in[2];
  const float* ea = (const float*)d_in[3];
  const float* Wi = (const float*)d_in[4];
  const float* bi = (const float*)d_in[5];
  const float* Wc = (const float*)d_in[6];
  const float* bc = (const float*)d_in[7];
  float* out = (float*)d_out;

  char* w = (char*)d_ws;
  size_t off = 0;
  auto alloc = [&](size_t bytes) {
    void* p = w + off;
    off += (bytes + 511) & ~(size_t)511;
    return p;
  };
  float* deg           = (float*)alloc(N_NODES * 4);
  float* dinv          = (float*)alloc(N_NODES * 4);
  int* counts          = (int*)alloc(N_NODES * 4);
  int* cursor          = (int*)alloc(N_NODES * 4);
  int* row_ptr         = (int*)alloc((N_NODES + 1) * 4);
  int2* csr            = (int2*)alloc((size_t)N_EDGES * 8);
  unsigned short* WiT  = (unsigned short*)alloc(256 * 256 * 2);
  unsigned short* WcT  = (unsigned short*)alloc(512 * 256 * 2);
  float* bcp           = (float*)alloc(512 * 4);
  unsigned short* AhAc = (unsigned short*)alloc((size_t)N_NODES * 256 * 2);
  unsigned short* hbf  = (unsigned short*)alloc((size_t)N_NODES * 128 * 2);
  float* c_cur         = (float*)alloc((size_t)N_NODES * 128 * 4);

  const int NB_E = (N_EDGES + 255) / 256;   // 1250
  const int NB_AGG = N_NODES * 64 / 256;    // 5000 (1 node/wave, init)
  const int NB_AGG2 = N_NODES * 32 / 256;   // 2500 (2 nodes/wave, step)
  const int MB = (N_NODES + 127) / 128;     // 157

  k_prologue<<<512, 256, 0, stream>>>(Wi, Wc, bc, WiT, WcT, bcp, deg, counts);
  k_deg<<<NB_E, 256, 0, stream>>>(ei, ea, deg, counts);
  k_scan<<<1, 1024, 0, stream>>>(counts, deg, dinv, row_ptr, cursor);
  k_fill<<<NB_E, 256, 0, stream>>>(ei, ea, dinv, cursor, csr);

  k_agg_init<<<NB_AGG, 256, 0, stream>>>(h, c, (unsigned int*)AhAc, dinv,
                                         row_ptr, csr);
  // states = elu([Ah|Ac]@Wi + bi) -> hbf, c_cur
  k_gemm<0, 256, 256><<<dim3(MB, 2), 256, 0, stream>>>(
      AhAc, WiT, bi, c_cur, hbf, nullptr);

  for (int t = 0; t < SEQ; ++t) {
    // Aht written into AhAc cols 128..255; gates = [Ah|Aht] @ [W1;W2] + bcp
    k_agg_step<<<NB_AGG2, 256, 0, stream>>>((unsigned int*)hbf,
                                            (unsigned int*)AhAc, dinv, row_ptr,
                                            csr);
    k_gemm<2, 256, 256><<<dim3(MB, 4), 256, 0, stream>>>(
        AhAc, WcT, bcp, c_cur, hbf, out + (size_t)t * N_NODES * 128);
  }
}